// Round 7
// baseline (60.445 us; speedup 1.0000x reference)
//
#include <hip/hip_runtime.h>
#include <math.h>

#define RG 61
#define CG 61
#define NP 3721           // RG*CG
#define NSEG 3722         // NP+1
#define NCLS 10
#define THRESHV 0.7f
#define BIGI 0x3FFFFFFF

// logits kernel geometry: block = (r, ks). ks-slice = 8 window rows = 1536
// K-elements = 768 pairs. 512 threads = (kg in [0,64)) x (pg in [0,8)).
// Each thread: 8 patch-slots (c = pg + 8p), 12 pairs (3 per chunk, 4 chunks).
#define NBLK 488          // 61 * 8
#define WSLICE 15360      // floats per ks W-slice (1536 * 10)
#define WCHUNK 3840       // floats per chunk (2 window rows * 192 * 10)
#define WBYTES 491520     // 12288*10*4

typedef const __attribute__((address_space(1))) void* gas1;
typedef __attribute__((address_space(3))) void* las3;
#define GLD16(G, L) __builtin_amdgcn_global_load_lds((gas1)(G), (las3)(L), 16, 0, 0)
#define WAITV(N) { asm volatile("s_waitcnt vmcnt(" #N ")" ::: "memory"); \
                   __builtin_amdgcn_sched_barrier(0); }
#define BAR() __builtin_amdgcn_s_barrier()

// ---------------------------------------------------------------------------
// Kernel 1: partial logits. img slice (8 rows x 3072 f = 96KB) staged once via
// global_load_lds; W slice streamed in 4 chunks through a 2x16KB LDS dbuf with
// counted vmcnt(2) (never drained in-loop) + raw s_barrier. Inner loop is pure
// LDS reads + FMA (W b128 bank-disjoint across kg; acc[8][10] per thread).
// ---------------------------------------------------------------------------
#define STAGE_W(BUF, CH) { \
    _Pragma("unroll") \
    for (int j2 = 0; j2 < 2; ++j2) { \
        const int m_ = wv * 2 + j2; \
        long gb_ = (long)(wbase + (CH) * WCHUNK) * 4 + m_ * 1024 + lane * 16; \
        if (gb_ > WBYTES - 16) gb_ = WBYTES - 16; \
        GLD16((const char*)W + gb_, (char*)s_w + (BUF) * 16384 + m_ * 1024); \
    } }

#define COMPUTE(CH, BUF) { \
    const float* wsel = s_w + (BUF) * 4096; \
    _Pragma("unroll") \
    for (int j = 0; j < 3; ++j) { \
        const int pair = kg + 64 * j;             /* [0,192) */ \
        const int wr   = pair / 96; \
        const int rem2 = (pair - wr * 96) * 2; \
        const float4 A0 = *(const float4*)(wsel + pair * 20); \
        const float4 A1 = *(const float4*)(wsel + pair * 20 + 4); \
        const float4 A2 = *(const float4*)(wsel + pair * 20 + 8); \
        const float4 A3 = *(const float4*)(wsel + pair * 20 + 12); \
        const float4 A4 = *(const float4*)(wsel + pair * 20 + 16); \
        const float w0_[NCLS] = {A0.x,A0.y,A0.z,A0.w,A1.x,A1.y,A1.z,A1.w,A2.x,A2.y}; \
        const float w1_[NCLS] = {A2.z,A2.w,A3.x,A3.y,A3.z,A3.w,A4.x,A4.y,A4.z,A4.w}; \
        const float* xrow = s_img + ((CH) * 2 + wr) * 3072 + rem2; \
        _Pragma("unroll") \
        for (int p = 0; p < 8; ++p) { \
            const int cc_ = pg + 8 * p; \
            const int cx_ = cc_ > 60 ? 60 : cc_;  /* dup c=60, discarded later */ \
            const float2 x = *(const float2*)(xrow + cx_ * 48); \
            _Pragma("unroll") \
            for (int k = 0; k < NCLS; ++k) { \
                acc[p][k] = fmaf(x.x, w0_[k], acc[p][k]); \
                acc[p][k] = fmaf(x.y, w1_[k], acc[p][k]); \
            } } } }

__global__ __launch_bounds__(512, 2) void wod_logits_part(
    const float* __restrict__ img,   // (1024,1024,3)
    const float* __restrict__ W,     // (12288,10)
    float* __restrict__ part)        // (488, 640)
{
    __shared__ float s_img[24576];   // 8 rows x 3072 f = 96KB
    __shared__ float s_w[8192];      // 2 x 4096 f = 32KB  (total 128KiB)

    const int tid  = threadIdx.x;
    const int wv   = tid >> 6;
    const int lane = tid & 63;
    const int kg   = tid >> 3;       // [0,64)
    const int pg   = tid & 7;        // [0,8)

    // bijective XCD swizzle: 488 = 8*61; same-XCD blocks share img rows in L2
    const int o  = (blockIdx.x & 7) * 61 + (blockIdx.x >> 3);
    const int r  = o >> 3;           // [0,61)
    const int ks = o & 7;            // [0,8)
    const int R0 = 16 * r + 8 * ks;  // first image row (<= 1016)
    const int wbase = ks * WSLICE;   // float offset of W slice

    // ---- stage img slice: 96KB = 96 x 1KB DMA chunks (12 instr per wave) ----
    const char* gimg = (const char*)(img + (size_t)R0 * 3072);
    #pragma unroll
    for (int j = 0; j < 12; ++j) {
        const int q = wv * 12 + j;
        GLD16(gimg + q * 1024 + lane * 16, (char*)s_img + q * 1024);
    }

    float acc[8][NCLS];
    #pragma unroll
    for (int p = 0; p < 8; ++p)
        #pragma unroll
        for (int k = 0; k < NCLS; ++k) acc[p][k] = 0.f;

    STAGE_W(0, 0)                    // +2 instr  (img 12 + 2 outstanding)
    STAGE_W(1, 1)                    // +2 instr
    WAITV(2)                         // img + chunk0 done; chunk1 in flight
    BAR();
    COMPUTE(0, 0)
    BAR();                           // all waves done reading buf0
    STAGE_W(0, 2)
    WAITV(2)                         // chunk1 done; chunk2 in flight
    BAR();
    COMPUTE(1, 1)
    BAR();
    STAGE_W(1, 3)
    WAITV(2)                         // chunk2 done; chunk3 in flight
    BAR();
    COMPUTE(2, 0)
    BAR();
    WAITV(0)                         // chunk3 done
    BAR();
    COMPUTE(3, 1)

    // ---- reduce over kg: shuffle within wave (8 kg per wave), then LDS ----
    #pragma unroll
    for (int p = 0; p < 8; ++p)
        #pragma unroll
        for (int k = 0; k < NCLS; ++k) {
            float v = acc[p][k];
            v += __shfl_down(v, 8);
            v += __shfl_down(v, 16);
            v += __shfl_down(v, 32);
            acc[p][k] = v;
        }
    __syncthreads();                 // compute done; reuse s_img as scratch
    if (lane < 8) {                  // lane == pg here
        const int row = wv * 8 + lane;
        #pragma unroll
        for (int p = 0; p < 8; ++p)
            #pragma unroll
            for (int k = 0; k < NCLS; ++k)
                s_img[row * 80 + p * 10 + k] = acc[p][k];
    }
    __syncthreads();
    const int ob = o * 640;
    for (int o2 = tid; o2 < 640; o2 += 512) {
        const int c   = o2 / 10;
        const int k   = o2 - c * 10;
        const int pg_ = c & 7, pp = c >> 3;
        float sum = 0.f;
        #pragma unroll
        for (int w = 0; w < 8; ++w)
            sum += s_img[(w * 8 + pg_) * 80 + pp * 10 + k];
        part[ob + o2] = sum;
    }
}

// ---------------------------------------------------------------------------
// Kernel 2: sum 8 ks-slices + bias + softmax + prob + mask.
// ---------------------------------------------------------------------------
__global__ __launch_bounds__(256) void wod_reduce(
    const float* __restrict__ part,   // (488, 640)
    const float* __restrict__ bias,   // (10)
    float* __restrict__ out_prob,     // (61,61,10)
    int* __restrict__ mask)           // (10,3721)
{
    const int cell = blockIdx.x * 256 + threadIdx.x;
    if (cell >= NP) return;
    const int r = cell / CG;
    const int c = cell - r * CG;

    float lg[NCLS];
    #pragma unroll
    for (int k = 0; k < NCLS; ++k) lg[k] = bias[k];
    #pragma unroll
    for (int ks = 0; ks < 8; ++ks) {
        const int base = (r * 8 + ks) * 640 + c * 10;
        #pragma unroll
        for (int k = 0; k < NCLS; ++k) lg[k] += part[base + k];
    }

    float m = -1e30f;
    #pragma unroll
    for (int k = 0; k < NCLS; ++k) m = fmaxf(m, lg[k]);
    float ex[NCLS], sm = 0.f;
    #pragma unroll
    for (int k = 0; k < NCLS; ++k) { ex[k] = expf(lg[k] - m); sm += ex[k]; }
    const float inv = 1.f / sm;
    const int base = cell * NCLS;
    #pragma unroll
    for (int k = 0; k < NCLS; ++k) {
        const float pr = ex[k] * inv;
        out_prob[base + k] = pr;
        mask[k * NP + cell] = (pr > THRESHV) ? 1 : 0;
    }
}

// ---------------------------------------------------------------------------
// Kernel 3: connected components (min-label propagation in LDS) + labels +
// boxes + valid, all fused. One block per class.
// ---------------------------------------------------------------------------
__global__ __launch_bounds__(256) void wod_cc(
    const int* __restrict__ mask,     // (10,3721)
    float* __restrict__ out_lbl,      // (61,61,10) as float
    float* __restrict__ out_box,      // (10,3722,4)
    float* __restrict__ out_valid)    // (10,3722)
{
    const int k = blockIdx.x;
    const int tid = threadIdx.x;
    __shared__ int lbl[NP];
    __shared__ int ext0[NSEG], ext1[NSEG];
    __shared__ int changed;

    const int* mk = mask + k * NP;
    for (int idx = tid; idx < NP; idx += 256)
        lbl[idx] = mk[idx] ? (idx + 1) : 0;
    if (tid == 0) changed = 0;
    __syncthreads();

    for (;;) {
        for (int idx = tid; idx < NP; idx += 256) {
            int v = lbl[idx];
            if (v) {
                const int rr = idx / CG;
                const int cc = idx - rr * CG;
                int best = v;
                if (rr > 0)      { int n = lbl[idx - CG]; if (n && n < best) best = n; }
                if (rr < RG - 1) { int n = lbl[idx + CG]; if (n && n < best) best = n; }
                if (cc > 0)      { int n = lbl[idx - 1];  if (n && n < best) best = n; }
                if (cc < CG - 1) { int n = lbl[idx + 1];  if (n && n < best) best = n; }
                if (best < v) { lbl[idx] = best; changed = 1; }
            }
        }
        __syncthreads();
        const bool stop = (changed == 0);
        __syncthreads();           // all reads of `changed` done before reset
        if (stop) break;
        if (tid == 0) changed = 0;
        __syncthreads();
    }

    // labels out (transposed to (r,c,k))
    for (int idx = tid; idx < NP; idx += 256)
        out_lbl[idx * NCLS + k] = (float)lbl[idx];

    float* boxk = out_box + k * NSEG * 4;
    float* valk = out_valid + k * NSEG;

    // pass 1: rmin / cmin
    for (int s2 = tid; s2 < NSEG; s2 += 256) { ext0[s2] = BIGI; ext1[s2] = BIGI; }
    __syncthreads();
    for (int idx = tid; idx < NP; idx += 256) {
        const int v = lbl[idx];
        if (v) {
            const int rr = idx / CG, cc = idx - rr * CG;
            atomicMin(&ext0[v], rr);
            atomicMin(&ext1[v], cc);
        }
    }
    __syncthreads();
    for (int s2 = tid; s2 < NSEG; s2 += 256) {
        const bool valid = (s2 > 0) && (ext0[s2] != BIGI);
        boxk[s2 * 4 + 0] = valid ? (float)(ext0[s2] - 1) : -1.f;
        boxk[s2 * 4 + 1] = valid ? (float)(ext1[s2] - 1) : -1.f;
        valk[s2] = valid ? 1.f : 0.f;
    }
    __syncthreads();

    // pass 2: rmax / cmax
    for (int s2 = tid; s2 < NSEG; s2 += 256) { ext0[s2] = -1; ext1[s2] = -1; }
    __syncthreads();
    for (int idx = tid; idx < NP; idx += 256) {
        const int v = lbl[idx];
        if (v) {
            const int rr = idx / CG, cc = idx - rr * CG;
            atomicMax(&ext0[v], rr);
            atomicMax(&ext1[v], cc);
        }
    }
    __syncthreads();
    for (int s2 = tid; s2 < NSEG; s2 += 256) {
        const bool valid = (s2 > 0) && (ext0[s2] >= 0);
        boxk[s2 * 4 + 2] = valid ? (float)(ext0[s2] + 1) : -1.f;
        boxk[s2 * 4 + 3] = valid ? (float)(ext1[s2] + 1) : -1.f;
    }
}

// ---------------------------------------------------------------------------
extern "C" void kernel_launch(void* const* d_in, const int* in_sizes, int n_in,
                              void* d_out, int out_size, void* d_ws, size_t ws_size,
                              hipStream_t stream) {
    (void)in_sizes; (void)n_in; (void)out_size; (void)ws_size;
    const float* img = (const float*)d_in[0];
    const float* W   = (const float*)d_in[1];
    const float* b   = (const float*)d_in[2];

    float* out       = (float*)d_out;
    float* out_prob  = out;                       // 37210
    float* out_lbl   = out + 37210;               // 37210
    float* out_box   = out + 74420;               // 148880
    float* out_valid = out + 223300;              // 37220

    int*   mask = (int*)d_ws;                     // 10*3721 ints
    float* part = (float*)((int*)d_ws + NCLS * NP); // 488*640 floats (~1.25MB)

    hipLaunchKernelGGL(wod_logits_part, dim3(NBLK), dim3(512), 0, stream,
                       img, W, part);
    hipLaunchKernelGGL(wod_reduce, dim3((NP + 255) / 256), dim3(256), 0, stream,
                       part, b, out_prob, mask);
    hipLaunchKernelGGL(wod_cc, dim3(NCLS), dim3(256), 0, stream,
                       mask, out_lbl, out_box, out_valid);
}

// Round 10
// 47.165 us; speedup vs baseline: 1.2816x; 1.2816x over previous
//
#include <hip/hip_runtime.h>
#include <math.h>

#define RG 61
#define CG 61
#define NP 3721           // RG*CG
#define NSEG 3722         // NP+1
#define NCLS 10
#define THRESHV 0.7f
#define BIGI 0x3FFFFFFF

#define NKQ 16            // K-quarters per output row; each block does 4 window rows
#define NBLK (RG*NKQ)     // 976
#define PAD 54            // img chunk stride in floats (4*54 % 32 = 24 -> 2-way max)

// ---------------------------------------------------------------------------
// Kernel 1: partial logits. Block = (r, kq). Loops m=0..3 over window rows
// wr = 4*kq+m  (so all 64 window rows are covered across kq — the round-8/9
// bug was covering only rows 0..15). Per sub-step: stage img row 16r+wr
// (chunked [64][PAD]) + W rows wr*192..+192 (pair-rows of 80B) into LDS,
// then pure LDS+FMA compute accumulating acc over m and s.
// Thread map: wave wv=(kh,h); lane=(g,qd). P=4 patches/lane (c = h*32+qd*4+t).
// Per s-step: 5 b128 W (8 distinct addrs, broadcast within qd-groups) +
// 4 b64 img (<=2-way via PAD) feeding 80 FMAs. 26.6KB LDS -> 4 blocks/CU.
// ---------------------------------------------------------------------------
__global__ __launch_bounds__(256, 4) void wod_logits_part(
    const float* __restrict__ img,   // (1024,1024,3)
    const float* __restrict__ W,     // (12288,10)
    float* __restrict__ part)        // (976, 640)
{
    __shared__ float simg[64 * PAD]; // 13824 B
    __shared__ float sw[1920];       // 7680 B
    __shared__ float scr[1280];      // 5120 B reduction scratch

    const int tid = threadIdx.x;
    // bijective XCD swizzle: 976 = 8*122
    const int o  = (blockIdx.x & 7) * 122 + (blockIdx.x >> 3);
    const int r  = o >> 4;           // output row  [0,61)
    const int kq = o & 15;           // K-quarter   [0,16)

    const int wv = tid >> 6, lane = tid & 63;
    const int g  = lane >> 3, qd = lane & 7;
    const int h  = wv & 1,  kh = wv >> 1;
    const int cb = h * 32 + qd * 4;

    int cbase[4];
    #pragma unroll
    for (int t = 0; t < 4; ++t) {
        const int c = cb + t;
        cbase[t] = (c > 60 ? 60 : c) * PAD;   // dup slots clamped (discarded)
    }

    float acc[4][NCLS];
    #pragma unroll
    for (int t = 0; t < 4; ++t)
        #pragma unroll
        for (int k = 0; k < NCLS; ++k) acc[t][k] = 0.f;

    for (int m = 0; m < 4; ++m) {
        if (m) __syncthreads();          // previous sub-step's compute done
        const int wr = 4 * kq + m;       // window row [0,64)

        // ---- stage W rows wr*192 .. +192 (1920 contiguous floats) ----
        const float* wsrc = W + wr * 1920;
        for (int v = tid; v < 480; v += 256)
            *(float4*)(sw + v * 4) = *(const float4*)(wsrc + v * 4);

        // ---- stage img row 16r+wr, chunked ----
        const float* isrc = img + (size_t)(16 * r + wr) * 3072;
        for (int v = tid; v < 768; v += 256) {
            const float4 x4 = *(const float4*)(isrc + v * 4);
            const int p0 = v * 4;
            const int ch = p0 / 48;      // p0%48 in {0,4,..,44}: never crosses
            float* d = simg + ch * PAD + (p0 - ch * 48);
            d[0] = x4.x; d[1] = x4.y; d[2] = x4.z; d[3] = x4.w;
        }
        __syncthreads();

        // ---- compute: 6 s-steps, pure LDS + FMA ----
        #pragma unroll 2
        for (int s = 0; s < 6; ++s) {
            const int pr = kh * 48 + s * 8 + g;     // pair index [0,96)
            const float* wp = sw + pr * 20;         // 80B-aligned
            const float4 A0 = *(const float4*)(wp);
            const float4 A1 = *(const float4*)(wp + 4);
            const float4 A2 = *(const float4*)(wp + 8);
            const float4 A3 = *(const float4*)(wp + 12);
            const float4 A4 = *(const float4*)(wp + 16);
            const int q0 = pr * 2;                  // [0,192), even
            const int cq = q0 / 48;
            const float* xb = simg + cq * PAD + (q0 - cq * 48);
            float2 x[4];
            #pragma unroll
            for (int t = 0; t < 4; ++t)
                x[t] = *(const float2*)(xb + cbase[t]);
            const float w0[NCLS] = {A0.x,A0.y,A0.z,A0.w,A1.x,A1.y,A1.z,A1.w,A2.x,A2.y};
            const float w1[NCLS] = {A2.z,A2.w,A3.x,A3.y,A3.z,A3.w,A4.x,A4.y,A4.z,A4.w};
            #pragma unroll
            for (int t = 0; t < 4; ++t)
                #pragma unroll
                for (int k = 0; k < NCLS; ++k) {
                    acc[t][k] = fmaf(x[t].x, w0[k], acc[t][k]);
                    acc[t][k] = fmaf(x[t].y, w1[k], acc[t][k]);
                }
        }
    }

    // ---- reduce over g (8 subgroups) within wave ----
    #pragma unroll
    for (int t = 0; t < 4; ++t)
        #pragma unroll
        for (int k = 0; k < NCLS; ++k) {
            float v = acc[t][k];
            v += __shfl_down(v, 8);
            v += __shfl_down(v, 16);
            v += __shfl_down(v, 32);
            acc[t][k] = v;
        }
    if (g == 0) {                       // lane < 8, lane == qd
        #pragma unroll
        for (int t = 0; t < 4; ++t)
            #pragma unroll
            for (int k = 0; k < NCLS; ++k)
                scr[wv * 320 + qd * 40 + t * 10 + k] = acc[t][k];
    }
    __syncthreads();
    // ---- combine K-halves (waves h and h+2), store ALL 640 partials ----
    for (int o2 = tid; o2 < 640; o2 += 256) {
        const int c = o2 / 10, k = o2 - c * 10;
        const int h2 = c >> 5, q2 = (c >> 2) & 7, t2 = c & 3;
        const int idx = q2 * 40 + t2 * 10 + k;
        part[o * 640 + o2] = scr[h2 * 320 + idx] + scr[(h2 + 2) * 320 + idx];
    }
}

// ---------------------------------------------------------------------------
// Kernel 2: sum 16 kq-slices + bias + softmax + prob + mask.
// ---------------------------------------------------------------------------
__global__ __launch_bounds__(256) void wod_reduce(
    const float* __restrict__ part,   // (976, 640)
    const float* __restrict__ bias,   // (10)
    float* __restrict__ out_prob,     // (61,61,10)
    int* __restrict__ mask)           // (10,3721)
{
    const int cell = blockIdx.x * 256 + threadIdx.x;
    if (cell >= NP) return;
    const int r = cell / CG;
    const int c = cell - r * CG;

    float lg[NCLS];
    #pragma unroll
    for (int k = 0; k < NCLS; ++k) lg[k] = bias[k];
    const float* pb = part + (size_t)r * 16 * 640 + c * 10;
    #pragma unroll
    for (int kq = 0; kq < 16; ++kq)
        #pragma unroll
        for (int k = 0; k < NCLS; ++k) lg[k] += pb[kq * 640 + k];

    float m = -1e30f;
    #pragma unroll
    for (int k = 0; k < NCLS; ++k) m = fmaxf(m, lg[k]);
    float ex[NCLS], sm = 0.f;
    #pragma unroll
    for (int k = 0; k < NCLS; ++k) { ex[k] = expf(lg[k] - m); sm += ex[k]; }
    const float inv = 1.f / sm;
    const int base = cell * NCLS;
    #pragma unroll
    for (int k = 0; k < NCLS; ++k) {
        const float pr = ex[k] * inv;
        out_prob[base + k] = pr;
        mask[k * NP + cell] = (pr > THRESHV) ? 1 : 0;
    }
}

// ---------------------------------------------------------------------------
// Kernel 3: connected components (min-label propagation in LDS) + labels +
// boxes + valid, all fused. One block per class.
// ---------------------------------------------------------------------------
__global__ __launch_bounds__(256) void wod_cc(
    const int* __restrict__ mask,     // (10,3721)
    float* __restrict__ out_lbl,      // (61,61,10) as float
    float* __restrict__ out_box,      // (10,3722,4)
    float* __restrict__ out_valid)    // (10,3722)
{
    const int k = blockIdx.x;
    const int tid = threadIdx.x;
    __shared__ int lbl[NP];
    __shared__ int ext0[NSEG], ext1[NSEG];
    __shared__ int changed;

    const int* mk = mask + k * NP;
    for (int idx = tid; idx < NP; idx += 256)
        lbl[idx] = mk[idx] ? (idx + 1) : 0;
    if (tid == 0) changed = 0;
    __syncthreads();

    for (;;) {
        for (int idx = tid; idx < NP; idx += 256) {
            int v = lbl[idx];
            if (v) {
                const int rr = idx / CG;
                const int cc = idx - rr * CG;
                int best = v;
                if (rr > 0)      { int n = lbl[idx - CG]; if (n && n < best) best = n; }
                if (rr < RG - 1) { int n = lbl[idx + CG]; if (n && n < best) best = n; }
                if (cc > 0)      { int n = lbl[idx - 1];  if (n && n < best) best = n; }
                if (cc < CG - 1) { int n = lbl[idx + 1];  if (n && n < best) best = n; }
                if (best < v) { lbl[idx] = best; changed = 1; }
            }
        }
        __syncthreads();
        const bool stop = (changed == 0);
        __syncthreads();           // all reads of `changed` done before reset
        if (stop) break;
        if (tid == 0) changed = 0;
        __syncthreads();
    }

    // labels out (transposed to (r,c,k))
    for (int idx = tid; idx < NP; idx += 256)
        out_lbl[idx * NCLS + k] = (float)lbl[idx];

    float* boxk = out_box + k * NSEG * 4;
    float* valk = out_valid + k * NSEG;

    // pass 1: rmin / cmin
    for (int s2 = tid; s2 < NSEG; s2 += 256) { ext0[s2] = BIGI; ext1[s2] = BIGI; }
    __syncthreads();
    for (int idx = tid; idx < NP; idx += 256) {
        const int v = lbl[idx];
        if (v) {
            const int rr = idx / CG, cc = idx - rr * CG;
            atomicMin(&ext0[v], rr);
            atomicMin(&ext1[v], cc);
        }
    }
    __syncthreads();
    for (int s2 = tid; s2 < NSEG; s2 += 256) {
        const bool valid = (s2 > 0) && (ext0[s2] != BIGI);
        boxk[s2 * 4 + 0] = valid ? (float)(ext0[s2] - 1) : -1.f;
        boxk[s2 * 4 + 1] = valid ? (float)(ext1[s2] - 1) : -1.f;
        valk[s2] = valid ? 1.f : 0.f;
    }
    __syncthreads();

    // pass 2: rmax / cmax
    for (int s2 = tid; s2 < NSEG; s2 += 256) { ext0[s2] = -1; ext1[s2] = -1; }
    __syncthreads();
    for (int idx = tid; idx < NP; idx += 256) {
        const int v = lbl[idx];
        if (v) {
            const int rr = idx / CG, cc = idx - rr * CG;
            atomicMax(&ext0[v], rr);
            atomicMax(&ext1[v], cc);
        }
    }
    __syncthreads();
    for (int s2 = tid; s2 < NSEG; s2 += 256) {
        const bool valid = (s2 > 0) && (ext0[s2] >= 0);
        boxk[s2 * 4 + 2] = valid ? (float)(ext0[s2] + 1) : -1.f;
        boxk[s2 * 4 + 3] = valid ? (float)(ext1[s2] + 1) : -1.f;
    }
}

// ---------------------------------------------------------------------------
extern "C" void kernel_launch(void* const* d_in, const int* in_sizes, int n_in,
                              void* d_out, int out_size, void* d_ws, size_t ws_size,
                              hipStream_t stream) {
    (void)in_sizes; (void)n_in; (void)out_size; (void)ws_size;
    const float* img = (const float*)d_in[0];
    const float* W   = (const float*)d_in[1];
    const float* b   = (const float*)d_in[2];

    float* out       = (float*)d_out;
    float* out_prob  = out;                       // 37210
    float* out_lbl   = out + 37210;               // 37210
    float* out_box   = out + 74420;               // 148880
    float* out_valid = out + 223300;              // 37220

    int*   mask = (int*)d_ws;                        // 10*3721 ints
    float* part = (float*)((int*)d_ws + NCLS * NP);  // 976*640 floats (~2.5MB)

    hipLaunchKernelGGL(wod_logits_part, dim3(NBLK), dim3(256), 0, stream,
                       img, W, part);
    hipLaunchKernelGGL(wod_reduce, dim3((NP + 255) / 256), dim3(256), 0, stream,
                       part, b, out_prob, mask);
    hipLaunchKernelGGL(wod_cc, dim3(NCLS), dim3(256), 0, stream,
                       mask, out_lbl, out_box, out_valid);
}